// Round 19
// baseline (979.513 us; speedup 1.0000x reference)
//
#include <hip/hip_runtime.h>
#include <stdint.h>

#define BS 8
#define NN 400
#define HH 768
#define RR 46
#define MB 416       // per-b M chunk in h1T rows (13 K-steps x 32)
#define APAD 448     // att storage row width: 448*2B = 896B = 7 full cache lines
#define MFLAT2 3328  // 8 * 416: per-b padded flat M
#define LDW2 3328    // h1T row width == MFLAT2

typedef _Float16 half8 __attribute__((ext_vector_type(8)));
typedef _Float16 half4v __attribute__((ext_vector_type(4)));
typedef float floatx4 __attribute__((ext_vector_type(4)));

__device__ __forceinline__ void async16(const void* g, void* l) {
  __builtin_amdgcn_global_load_lds((const __attribute__((address_space(1))) uint32_t*)g,
                                   (__attribute__((address_space(3))) uint32_t*)l, 16, 0, 0);
}

// bijective XCD swizzle (m204)
__device__ __forceinline__ int xcd_work(int flat, int nwg) {
  int q = nwg >> 3, rem = nwg & 7;
  int xcd = flat & 7, slot = flat >> 3;
  return (xcd < rem ? xcd * (q + 1) : rem * (q + 1) + (xcd - rem) * q) + slot;
}

// counted vmcnt: count = min(ahead,2) * nl, nl = loads/step (wave-uniform)
__device__ __forceinline__ void vm_waitC(int count) {
  switch (count) {
    case 6: asm volatile("s_waitcnt vmcnt(6)" ::: "memory"); break;
    case 4: asm volatile("s_waitcnt vmcnt(4)" ::: "memory"); break;
    case 3: asm volatile("s_waitcnt vmcnt(3)" ::: "memory"); break;
    case 2: asm volatile("s_waitcnt vmcnt(2)" ::: "memory"); break;
    case 1: asm volatile("s_waitcnt vmcnt(1)" ::: "memory"); break;
    default: asm volatile("s_waitcnt vmcnt(0)" ::: "memory"); break;
  }
}
#define BAR_ONE() { asm volatile("s_barrier" ::: "memory"); __builtin_amdgcn_sched_barrier(0); }

// T2 swizzle: LDS(row, slot) holds global col-slot (slot ^ ((row>>1)&3)).
// Stager lane constant: slot_g = (lane&3) ^ ((lane>>3)&3)   [row = 16c + lane>>2]
// Reader lane constant: slot_l = (lane>>4) ^ ((lane>>1)&3)  [row = 16-aligned + (lane&15)]

// gemm_att K-step with valid-M fragment count mi (wave-uniform): skips garbage-row MFMAs
__device__ __forceinline__ void mma_tiles_mi(const _Float16* As, const _Float16* Bs, int lane,
                                             int wr, int wc, int mi, floatx4 acc[4][4]) {
  int arow = wr + (lane & 15);
  int brow = wc + (lane & 15);
  int kswz = ((lane >> 4) ^ ((lane >> 1) & 3)) * 8;
  half8 b[4];
#pragma unroll
  for (int j = 0; j < 4; ++j) b[j] = *(const half8*)&Bs[(brow + j * 16) * 32 + kswz];
#pragma unroll
  for (int i = 0; i < 4; ++i) {
    if (i < mi) {  // wave-uniform -> scalar branch
      half8 a = *(const half8*)&As[(arow + i * 16) * 32 + kswz];
#pragma unroll
      for (int j = 0; j < 4; ++j)
        acc[i][j] = __builtin_amdgcn_mfma_f32_16x16x32_f16(a, b[j], acc[i][j], 0, 0, 0);
    }
  }
}

// gemm_xw v2 K-step: wave owns 128m x 32n of a 256x128 tile; 10 ds_read + 16 MFMA
__device__ __forceinline__ void mma16b(const _Float16* As, const _Float16* Bs, int lane,
                                       int wr, int wc, floatx4 acc[8][2]) {
  int arow = wr + (lane & 15);
  int brow = wc + (lane & 15);
  int kswz = ((lane >> 4) ^ ((lane >> 1) & 3)) * 8;
  half8 a[8], b[2];
#pragma unroll
  for (int i = 0; i < 8; ++i) a[i] = *(const half8*)&As[(arow + i * 16) * 32 + kswz];
#pragma unroll
  for (int j = 0; j < 2; ++j) b[j] = *(const half8*)&Bs[(brow + j * 16) * 32 + kswz];
#pragma unroll
  for (int i = 0; i < 8; ++i)
#pragma unroll
    for (int j = 0; j < 2; ++j)
      acc[i][j] = __builtin_amdgcn_mfma_f32_16x16x32_f16(a[i], b[j], acc[i][j], 0, 0, 0);
}

// -------- W convert + transpose: W[l][r][h][k] (f32) -> Wt[l][r][k][h] (f16) --------
__global__ __launch_bounds__(256) void conv_w(const float* __restrict__ W, _Float16* __restrict__ Wt) {
  __shared__ float tl[32][33];
  int t = threadIdx.x;
  int lr = blockIdx.y;
  int tr = blockIdx.x / 24, tc = blockIdx.x % 24;
  const float* src = W + (size_t)lr * HH * HH;
  _Float16* dst = Wt + (size_t)lr * HH * HH;
  int rl = t >> 5, cl = t & 31;
#pragma unroll
  for (int j = 0; j < 4; ++j)
    tl[rl + 8 * j][cl] = src[(size_t)(tr * 32 + rl + 8 * j) * HH + tc * 32 + cl];
  __syncthreads();
#pragma unroll
  for (int j = 0; j < 4; ++j)
    dst[(size_t)(tc * 32 + rl + 8 * j) * HH + tr * 32 + cl] = (_Float16)tl[cl][rl + 8 * j];
}

// feature[b*400+m][h] f32 -> x16[b*416+m][h] f16, pad rows zeroed
__global__ void conv_x(const float* __restrict__ f, _Float16* __restrict__ x16) {
  int i4 = blockIdx.x * 256 + threadIdx.x;
  int row = i4 / 192;  // HH/4
  int c4 = i4 - row * 192;
  int b = row / 416;
  int m = row - b * 416;
  half4v h = {};
  if (m < NN) {
    float4 v = *(const float4*)(f + ((size_t)(b * NN + m) * HH) + c4 * 4);
    h[0] = (_Float16)v.x; h[1] = (_Float16)v.y; h[2] = (_Float16)v.z; h[3] = (_Float16)v.w;
  }
  *(half4v*)&x16[(size_t)row * HH + c4 * 4] = h;
}

// -------- softmax v3: sE flat = exp(adj row) verbatim; mask at sum/write; half4 out --------
__global__ __launch_bounds__(512) void att_softmax(const float* __restrict__ adj,
                                                   const float* __restrict__ dmask,
                                                   _Float16* __restrict__ att) {
  __shared__ _Float16 sE[NN * RR];  // 36800 B: sE[m*46+r] == flat adj-row order
  __shared__ float sM[NN];
  int t = threadIdx.x;
  int n = blockIdx.x, b = blockIdx.y;
  const float4* src = (const float4*)(adj + ((size_t)b * NN + n) * NN * RR);
  for (int i = t; i < NN; i += 512) sM[i] = dmask[b * NN + i];
  float4 v[9];
#pragma unroll
  for (int k = 0; k < 9; ++k) {
    int idx = t + k * 512;
    if (idx < NN * RR / 4) v[k] = src[idx];
  }
#pragma unroll
  for (int k = 0; k < 9; ++k) {
    int idx = t + k * 512;
    if (idx < NN * RR / 4) {
      half4v h;
      h[0] = (_Float16)__expf(v[k].x);
      h[1] = (_Float16)__expf(v[k].y);
      h[2] = (_Float16)__expf(v[k].z);
      h[3] = (_Float16)__expf(v[k].w);
      *(half4v*)&sE[idx * 4] = h;
    }
  }
  __syncthreads();
  int lane = t & 63, wid = t >> 6;
  for (int r = wid; r < RR; r += 8) {
    float s = 0.f;
    for (int m = lane; m < NN; m += 64)
      if (sM[m] > 0.5f) s += (float)sE[m * RR + r];
#pragma unroll
    for (int o = 32; o; o >>= 1) s += __shfl_xor(s, o);
    float inv = 1.0f / s;
    _Float16* orow = att + (((size_t)b * RR + r) * NN + n) * APAD;
    for (int m4 = lane * 4; m4 < APAD; m4 += 256) {
      half4v o = {};
#pragma unroll
      for (int e = 0; e < 4; ++e) {
        int m = m4 + e;
        if (m < NN && sM[m] > 0.5f) o[e] = (_Float16)((float)sE[m * RR + r] * inv);
      }
      *(half4v*)&orow[m4] = o;
    }
  }
}

// -------- GEMM C v2: 256m x 128n, 8 waves x (128x32), ring-3 = 72KB, 2 blocks/CU (R14) --------
__global__ __launch_bounds__(512, 4) void gemm_xw(const _Float16* __restrict__ x16,
                                                  const _Float16* __restrict__ Wt,
                                                  _Float16* __restrict__ h1T, int layer, int r0, int rbase) {
  extern __shared__ __align__(16) char smraw[];  // 3 x (A 16K + B 8K) = 72 KB
  int t = threadIdx.x;
  int work = xcd_work(blockIdx.x, gridDim.x);
  int r_i = work / 78;
  int rem = work - r_i * 78;
  int r = r0 + r_i;
  int mtile = rem / 6, ntile = rem % 6;  // 13 x 6
  const _Float16* Bp = Wt + ((size_t)layer * RR + r) * HH * HH;
  int lane = t & 63, w = t >> 6;
  int wr = (w >> 2) * 128, wc = (w & 3) * 32;
  floatx4 acc[8][2] = {};

  int swz = ((lane & 3) ^ ((lane >> 3) & 3)) * 8;
  int ga0 = mtile * 256 + w * 32 + (lane >> 2);
  int ga1 = ga0 + 16;
  int gb = ntile * 128 + w * 16 + (lane >> 2);
  const _Float16* pa0 = x16 + (size_t)ga0 * HH + swz;
  const _Float16* pa1 = x16 + (size_t)ga1 * HH + swz;
  const _Float16* pb = Bp + (size_t)gb * HH + swz;
  auto issue = [&](int buf) {
    _Float16* lA = (_Float16*)(smraw + buf * 24576) + (w * 2) * 512;
    _Float16* lB = (_Float16*)(smraw + buf * 24576 + 16384) + w * 512;
    async16(pa0, lA); async16(pa1, lA + 512);
    async16(pb, lB);
    pa0 += 32; pa1 += 32; pb += 32;
  };

  issue(0); issue(1);
  asm volatile("s_waitcnt vmcnt(3)" ::: "memory");
  BAR_ONE();
  int cur = 0, nxt = 2;
  for (int s = 0; s < 24; ++s) {
    if (s + 2 < 24) { issue(nxt); nxt = nxt == 2 ? 0 : nxt + 1; }
    char* cb = smraw + cur * 24576;
    __builtin_amdgcn_s_setprio(1);
    mma16b((const _Float16*)cb, (const _Float16*)(cb + 16384), lane, wr, wc, acc);
    __builtin_amdgcn_s_setprio(0);
    if (s + 1 < 24) {
      if (s + 2 < 24) { asm volatile("s_waitcnt vmcnt(3)" ::: "memory"); }
      else            { asm volatile("s_waitcnt vmcnt(0)" ::: "memory"); }
      BAR_ONE();
    }
    cur = cur == 2 ? 0 : cur + 1;
  }
  __syncthreads();

  _Float16* outl = (_Float16*)smraw + (size_t)w * 4096;
#pragma unroll
  for (int i = 0; i < 8; ++i) {
#pragma unroll
    for (int j = 0; j < 2; ++j) {
      int rl = i * 16 + (lane >> 4) * 4;
      int cl = j * 16 + (lane & 15);
      int pos = rl ^ ((cl & 7) << 3);
      half4v v = {(_Float16)acc[i][j][0], (_Float16)acc[i][j][1],
                  (_Float16)acc[i][j][2], (_Float16)acc[i][j][3]};
      *(half4v*)&outl[cl * 128 + pos] = v;
    }
  }
  _Float16* outp = h1T + (size_t)(r - rbase) * HH * LDW2;
  int gmb = mtile * 256 + wr;
  int gnb = ntile * 128 + wc;
#pragma unroll
  for (int p = 0; p < 8; ++p) {
    int c = p * 4 + (lane >> 4);
    int mq = (lane & 15) * 8;
    int mpos = mq ^ ((c & 7) << 3);
    half8 v = *(const half8*)&outl[c * 128 + mpos];
    *(half8*)&outp[(size_t)(gnb + c) * LDW2 + gmb + mq] = v;
  }
}

// -------- GEMM D: 256m x 128n, 8 waves x (64x64), ring-4 x 24KB, counted vmcnt,
//          mi-trim + garbage-wave A-stage skip (per-wave nl ledger) --------
__global__ __launch_bounds__(512, 2) void gemm_att(const _Float16* __restrict__ att,
                                                   const _Float16* __restrict__ h1T,
                                                   float* __restrict__ partials, size_t psz,
                                                   int rs, int rcount, int rbase, int accflag,
                                                   int ngroups) {
  extern __shared__ __align__(16) char smraw[];  // 4 x (A 16K + B 8K) = 96 KB
  int t = threadIdx.x;
  int work = xcd_work(blockIdx.x, gridDim.x);
  int ntile = work % 6;
  int tmp = work / 6;
  int mtile = tmp & 1; tmp >>= 1;
  int g = tmp % ngroups;
  int b = tmp / ngroups;
  int rbeg = rs + (g * rcount) / ngroups;
  int rend = rs + ((g + 1) * rcount) / ngroups;
  int nr = rend - rbeg;
  int total = nr * 13;
  float* part = partials + (size_t)g * psz;
  int lane = t & 63, w = t >> 6;
  int wr = (w >> 1) * 64, wc = (w & 1) * 64;  // wave owns 64m x 64n of 256x128
  // valid-M fragment count for this wave (wave-uniform)
  int mrem = NN - (mtile * 256 + wr);
  int mi = mrem >= 64 ? 4 : (mrem <= 0 ? 0 : (mrem + 15) >> 4);
  floatx4 acc[4][4] = {}, sum[4][4] = {};

  int swz = ((lane & 3) ^ ((lane >> 3) & 3)) * 8;
  int rowbase = mtile * 256 + w * 32;  // wave-uniform staging row base
  // A-chunk validity (post mi-trim, rows >= NN are never read by any wave)
  bool doA0 = rowbase < NN;
  bool doA1 = rowbase + 16 < NN;
  int nl = 1 + (doA0 ? 1 : 0) + (doA1 ? 1 : 0);  // loads/thread/step, wave-uniform
  int ga0 = rowbase + (lane >> 2);
  int ga1 = ga0 + 16;
  ga0 = ga0 > NN - 1 ? NN - 1 : ga0;  // clamp residual partial chunk
  ga1 = ga1 > NN - 1 ? NN - 1 : ga1;
  int gb = ntile * 128 + w * 16 + (lane >> 2);
  const _Float16* pa0 = att + ((size_t)b * RR + rbeg) * NN * APAD + (size_t)ga0 * APAD + swz;
  const _Float16* pa1 = att + ((size_t)b * RR + rbeg) * NN * APAD + (size_t)ga1 * APAD + swz;
  const _Float16* pb = h1T + (size_t)(rbeg - rbase) * HH * LDW2 + (size_t)gb * LDW2 + b * MB + swz;
  int nsk = 0;
  auto issue = [&](int buf) {
    _Float16* lA = (_Float16*)(smraw + buf * 24576) + (w * 2) * 512;
    _Float16* lB = (_Float16*)(smraw + buf * 24576 + 16384) + w * 512;
    if (doA0) async16(pa0, lA);
    if (doA1) async16(pa1, lA + 512);
    async16(pb, lB);
    if (++nsk == 13) {
      nsk = 0;
      pa0 += (size_t)NN * APAD - 384; pa1 += (size_t)NN * APAD - 384;
      pb += (size_t)HH * LDW2 - 384;
    } else { pa0 += 32; pa1 += 32; pb += 32; }
  };
  auto wait_ahead = [&](int ahead) {
    int a2 = ahead > 2 ? 2 : (ahead < 0 ? 0 : ahead);
    vm_waitC(a2 * nl);
  };

  issue(0); issue(1); issue(2);
  wait_ahead(2);
  BAR_ONE();
  int cks = 0;
  for (int s = 0; s < total; ++s) {
    if (s + 3 < total) issue((s + 3) & 3);
    char* cb = smraw + (s & 3) * 24576;
    __builtin_amdgcn_s_setprio(1);
    mma_tiles_mi((const _Float16*)cb, (const _Float16*)(cb + 16384), lane, wr, wc, mi, acc);
    __builtin_amdgcn_s_setprio(0);
    if (cks == 12) {
#pragma unroll
      for (int i = 0; i < 4; ++i) {
        if (i < mi) {
#pragma unroll
          for (int j = 0; j < 4; ++j) {
#pragma unroll
            for (int q2 = 0; q2 < 4; ++q2) sum[i][j][q2] += fmaxf(acc[i][j][q2], 0.0f);
            acc[i][j] = (floatx4){0.f, 0.f, 0.f, 0.f};
          }
        }
      }
      cks = 0;
    } else ++cks;
    if (s + 1 < total) {
      wait_ahead(total - s - 2);
      BAR_ONE();  // publishes buf s+1; step-s ds_reads retired before last MFMA issued
    }
  }
#pragma unroll
  for (int i = 0; i < 4; ++i) {
    if (i >= mi) continue;
    int rl = wr + i * 16 + (lane >> 4) * 4;
    int grow = mtile * 256 + rl;
#pragma unroll
    for (int j = 0; j < 4; ++j) {
      int gcol = ntile * 128 + wc + j * 16 + (lane & 15);
#pragma unroll
      for (int q2 = 0; q2 < 4; ++q2) {
        if (grow + q2 < NN) {
          size_t idx = ((size_t)b * NN + grow + q2) * HH + gcol;
          float v = sum[i][j][q2];
          if (accflag) v += part[idx];
          part[idx] = v;
        }
      }
    }
  }
}

// -------- LayerNorm over H of z = relu(sum_g partial[g]) / R --------
__global__ __launch_bounds__(256) void lnorm(const float* __restrict__ partials, size_t psz, int np,
                                             _Float16* __restrict__ x16, float* __restrict__ out) {
  int row = blockIdx.x;
  int t = threadIdx.x;
  int b = row / NN;
  int xrow = row + b * 16;
  float v[3];
  float s = 0.f, s2 = 0.f;
#pragma unroll
  for (int j = 0; j < 3; ++j) {
    float a = 0.f;
    for (int gidx = 0; gidx < np; ++gidx) a += partials[(size_t)gidx * psz + (size_t)row * HH + t + j * 256];
    v[j] = fmaxf(a, 0.f) * (1.0f / RR);
    s += v[j];
    s2 += v[j] * v[j];
  }
#pragma unroll
  for (int o = 32; o; o >>= 1) {
    s += __shfl_xor(s, o);
    s2 += __shfl_xor(s2, o);
  }
  __shared__ float rs_[4], rs2_[4];
  int lane = t & 63, wid = t >> 6;
  if (!lane) { rs_[wid] = s; rs2_[wid] = s2; }
  __syncthreads();
  s = rs_[0] + rs_[1] + rs_[2] + rs_[3];
  s2 = rs2_[0] + rs2_[1] + rs2_[2] + rs2_[3];
  float mu = s * (1.0f / HH);
  float var = s2 * (1.0f / HH) - mu * mu;
  float rstd = rsqrtf(var + 1e-5f);
#pragma unroll
  for (int j = 0; j < 3; ++j) {
    float o = (v[j] - mu) * rstd;
    out[(size_t)row * HH + t + j * 256] = o;
    x16[(size_t)xrow * HH + t + j * 256] = (_Float16)o;
  }
}

extern "C" void kernel_launch(void* const* d_in, const int* in_sizes, int n_in,
                              void* d_out, int out_size, void* d_ws, size_t ws_size,
                              hipStream_t stream) {
  const float* adj = (const float*)d_in[0];
  const float* feature = (const float*)d_in[1];
  const float* dmask = (const float*)d_in[2];
  const float* W = (const float*)d_in[3];
  float* out = (float*)d_out;

  (void)hipFuncSetAttribute((const void*)gemm_xw,
                            hipFuncAttributeMaxDynamicSharedMemorySize, 73728);
  (void)hipFuncSetAttribute((const void*)gemm_att,
                            hipFuncAttributeMaxDynamicSharedMemorySize, 98304);

  uintptr_t base = (uintptr_t)d_ws;
  uintptr_t p = base;
  auto alloc = [&](size_t bytes) -> void* {
    uintptr_t q = (p + 255) & ~(uintptr_t)255;
    p = q + bytes;
    return (void*)q;
  };
  _Float16* att = (_Float16*)alloc((size_t)BS * RR * NN * APAD * 2);  // 131.9 MB
  _Float16* Wt = (_Float16*)alloc((size_t)2 * RR * HH * HH * 2);      // 108.5 MB
  _Float16* x16 = (_Float16*)alloc((size_t)MFLAT2 * HH * 2);          // 5.1 MB
  size_t psz = (size_t)(BS * NN) * HH;
  size_t pszB = psz * 4;
  size_t used = p - base;
  size_t rem = ws_size > used ? ws_size - used : 0;
  size_t perR = (size_t)HH * LDW2 * 2;  // 5.11 MB / r
  size_t h1full = (size_t)RR * perR;    // 235 MB

  conv_w<<<dim3(576, 2 * RR), 256, 0, stream>>>(W, Wt);
  conv_x<<<MFLAT2 * HH / 4 / 256, 256, 0, stream>>>(feature, x16);
  att_softmax<<<dim3(NN, BS), 512, 0, stream>>>(adj, dmask, att);

  if (rem >= h1full + 4 * pszB + 512) {
    _Float16* h1T = (_Float16*)alloc(h1full);
    int ngroups = (int)(((ws_size - (p - base)) - 256) / pszB);
    if (ngroups > 8) ngroups = 8;
    float* partials = (float*)alloc((size_t)ngroups * pszB);
    for (int layer = 0; layer < 2; ++layer) {
      gemm_xw<<<78 * RR, 512, 73728, stream>>>(x16, Wt, h1T, layer, 0, 0);
      gemm_att<<<96 * ngroups, 512, 98304, stream>>>(att, h1T, partials, psz, 0, RR, 0, 0, ngroups);
      lnorm<<<BS * NN, 256, 0, stream>>>(partials, psz, ngroups, x16, out);
    }
  } else {
    float* partials = (float*)alloc(pszB);
    size_t rem2 = ws_size > (p - base) ? ws_size - (p - base) : 0;
    int RCmax = (int)(rem2 / perR);
    if (RCmax > RR) RCmax = RR;
    if (RCmax < 1) RCmax = 1;
    _Float16* h1T = (_Float16*)alloc((size_t)RCmax * perR);
    for (int layer = 0; layer < 2; ++layer) {
      for (int r0 = 0; r0 < RR; r0 += RCmax) {
        int rc = RR - r0 < RCmax ? RR - r0 : RCmax;
        gemm_xw<<<78 * rc, 512, 73728, stream>>>(x16, Wt, h1T, layer, r0, r0);
        gemm_att<<<96 * 1, 512, 98304, stream>>>(att, h1T, partials, psz, r0, rc, r0, r0 > 0, 1);
      }
      lnorm<<<BS * NN, 256, 0, stream>>>(partials, psz, 1, x16, out);
    }
  }
}

// Round 20
// 951.265 us; speedup vs baseline: 1.0297x; 1.0297x over previous
//
#include <hip/hip_runtime.h>
#include <stdint.h>

#define BS 8
#define NN 400
#define HH 768
#define RR 46
#define MB 416       // per-b M chunk in h1T rows (13 K-steps x 32)
#define APAD 448     // att storage row width: 448*2B = 896B = 7 full cache lines
#define MFLAT2 3328  // 8 * 416: per-b padded flat M
#define LDW2 3328    // h1T row width == MFLAT2

typedef _Float16 half8 __attribute__((ext_vector_type(8)));
typedef _Float16 half4v __attribute__((ext_vector_type(4)));
typedef float floatx4 __attribute__((ext_vector_type(4)));

__device__ __forceinline__ void async16(const void* g, void* l) {
  __builtin_amdgcn_global_load_lds((const __attribute__((address_space(1))) uint32_t*)g,
                                   (__attribute__((address_space(3))) uint32_t*)l, 16, 0, 0);
}

// bijective XCD swizzle (m204)
__device__ __forceinline__ int xcd_work(int flat, int nwg) {
  int q = nwg >> 3, rem = nwg & 7;
  int xcd = flat & 7, slot = flat >> 3;
  return (xcd < rem ? xcd * (q + 1) : rem * (q + 1) + (xcd - rem) * q) + slot;
}

// counted vmcnt for 3-load stage groups (ring-4 gemm_att)
__device__ __forceinline__ void vm_wait3(int ahead) {
  if (ahead >= 2) asm volatile("s_waitcnt vmcnt(6)" ::: "memory");
  else if (ahead == 1) asm volatile("s_waitcnt vmcnt(3)" ::: "memory");
  else asm volatile("s_waitcnt vmcnt(0)" ::: "memory");
}
#define BAR_ONE() { asm volatile("s_barrier" ::: "memory"); __builtin_amdgcn_sched_barrier(0); }

// T2 swizzle: LDS(row, slot) holds global col-slot (slot ^ ((row>>1)&3)).
// Stager lane constant: slot_g = (lane&3) ^ ((lane>>3)&3)   [row = 16c + lane>>2]
// Reader lane constant: slot_l = (lane>>4) ^ ((lane>>1)&3)  [row = 16-aligned + (lane&15)]

// gemm_att K-step with valid-M fragment count mi (wave-uniform): skips garbage-row MFMAs
__device__ __forceinline__ void mma_tiles_mi(const _Float16* As, const _Float16* Bs, int lane,
                                             int wr, int wc, int mi, floatx4 acc[4][4]) {
  int arow = wr + (lane & 15);
  int brow = wc + (lane & 15);
  int kswz = ((lane >> 4) ^ ((lane >> 1) & 3)) * 8;
  half8 b[4];
#pragma unroll
  for (int j = 0; j < 4; ++j) b[j] = *(const half8*)&Bs[(brow + j * 16) * 32 + kswz];
#pragma unroll
  for (int i = 0; i < 4; ++i) {
    if (i < mi) {  // wave-uniform -> scalar branch
      half8 a = *(const half8*)&As[(arow + i * 16) * 32 + kswz];
#pragma unroll
      for (int j = 0; j < 4; ++j)
        acc[i][j] = __builtin_amdgcn_mfma_f32_16x16x32_f16(a, b[j], acc[i][j], 0, 0, 0);
    }
  }
}

// gemm_xw v2 K-step: wave owns 128m x 32n of a 256x128 tile; 10 ds_read + 16 MFMA
__device__ __forceinline__ void mma16b(const _Float16* As, const _Float16* Bs, int lane,
                                       int wr, int wc, floatx4 acc[8][2]) {
  int arow = wr + (lane & 15);
  int brow = wc + (lane & 15);
  int kswz = ((lane >> 4) ^ ((lane >> 1) & 3)) * 8;
  half8 a[8], b[2];
#pragma unroll
  for (int i = 0; i < 8; ++i) a[i] = *(const half8*)&As[(arow + i * 16) * 32 + kswz];
#pragma unroll
  for (int j = 0; j < 2; ++j) b[j] = *(const half8*)&Bs[(brow + j * 16) * 32 + kswz];
#pragma unroll
  for (int i = 0; i < 8; ++i)
#pragma unroll
    for (int j = 0; j < 2; ++j)
      acc[i][j] = __builtin_amdgcn_mfma_f32_16x16x32_f16(a[i], b[j], acc[i][j], 0, 0, 0);
}

// -------- W convert + transpose: W[l][r][h][k] (f32) -> Wt[l][r][k][h] (f16) --------
__global__ __launch_bounds__(256) void conv_w(const float* __restrict__ W, _Float16* __restrict__ Wt) {
  __shared__ float tl[32][33];
  int t = threadIdx.x;
  int lr = blockIdx.y;
  int tr = blockIdx.x / 24, tc = blockIdx.x % 24;
  const float* src = W + (size_t)lr * HH * HH;
  _Float16* dst = Wt + (size_t)lr * HH * HH;
  int rl = t >> 5, cl = t & 31;
#pragma unroll
  for (int j = 0; j < 4; ++j)
    tl[rl + 8 * j][cl] = src[(size_t)(tr * 32 + rl + 8 * j) * HH + tc * 32 + cl];
  __syncthreads();
#pragma unroll
  for (int j = 0; j < 4; ++j)
    dst[(size_t)(tc * 32 + rl + 8 * j) * HH + tr * 32 + cl] = (_Float16)tl[cl][rl + 8 * j];
}

// feature[b*400+m][h] f32 -> x16[b*416+m][h] f16, pad rows zeroed
__global__ void conv_x(const float* __restrict__ f, _Float16* __restrict__ x16) {
  int i4 = blockIdx.x * 256 + threadIdx.x;
  int row = i4 / 192;  // HH/4
  int c4 = i4 - row * 192;
  int b = row / 416;
  int m = row - b * 416;
  half4v h = {};
  if (m < NN) {
    float4 v = *(const float4*)(f + ((size_t)(b * NN + m) * HH) + c4 * 4);
    h[0] = (_Float16)v.x; h[1] = (_Float16)v.y; h[2] = (_Float16)v.z; h[3] = (_Float16)v.w;
  }
  *(half4v*)&x16[(size_t)row * HH + c4 * 4] = h;
}

// -------- softmax v3: sE flat = exp(adj row) verbatim; mask at sum/write; half4 out --------
__global__ __launch_bounds__(512) void att_softmax(const float* __restrict__ adj,
                                                   const float* __restrict__ dmask,
                                                   _Float16* __restrict__ att) {
  __shared__ _Float16 sE[NN * RR];  // 36800 B: sE[m*46+r] == flat adj-row order
  __shared__ float sM[NN];
  int t = threadIdx.x;
  int n = blockIdx.x, b = blockIdx.y;
  const float4* src = (const float4*)(adj + ((size_t)b * NN + n) * NN * RR);
  for (int i = t; i < NN; i += 512) sM[i] = dmask[b * NN + i];
  float4 v[9];
#pragma unroll
  for (int k = 0; k < 9; ++k) {
    int idx = t + k * 512;
    if (idx < NN * RR / 4) v[k] = src[idx];
  }
#pragma unroll
  for (int k = 0; k < 9; ++k) {
    int idx = t + k * 512;
    if (idx < NN * RR / 4) {
      half4v h;
      h[0] = (_Float16)__expf(v[k].x);
      h[1] = (_Float16)__expf(v[k].y);
      h[2] = (_Float16)__expf(v[k].z);
      h[3] = (_Float16)__expf(v[k].w);
      *(half4v*)&sE[idx * 4] = h;
    }
  }
  __syncthreads();
  int lane = t & 63, wid = t >> 6;
  for (int r = wid; r < RR; r += 8) {
    float s = 0.f;
    for (int m = lane; m < NN; m += 64)
      if (sM[m] > 0.5f) s += (float)sE[m * RR + r];
#pragma unroll
    for (int o = 32; o; o >>= 1) s += __shfl_xor(s, o);
    float inv = 1.0f / s;
    _Float16* orow = att + (((size_t)b * RR + r) * NN + n) * APAD;
    for (int m4 = lane * 4; m4 < APAD; m4 += 256) {
      half4v o = {};
#pragma unroll
      for (int e = 0; e < 4; ++e) {
        int m = m4 + e;
        if (m < NN && sM[m] > 0.5f) o[e] = (_Float16)((float)sE[m * RR + r] * inv);
      }
      *(half4v*)&orow[m4] = o;
    }
  }
}

// -------- GEMM C v2: 256m x 128n, 8 waves x (128x32), ring-3 = 72KB, 2 blocks/CU (R14) --------
__global__ __launch_bounds__(512, 4) void gemm_xw(const _Float16* __restrict__ x16,
                                                  const _Float16* __restrict__ Wt,
                                                  _Float16* __restrict__ h1T, int layer, int r0, int rbase) {
  extern __shared__ __align__(16) char smraw[];  // 3 x (A 16K + B 8K) = 72 KB
  int t = threadIdx.x;
  int work = xcd_work(blockIdx.x, gridDim.x);
  int r_i = work / 78;
  int rem = work - r_i * 78;
  int r = r0 + r_i;
  int mtile = rem / 6, ntile = rem % 6;  // 13 x 6
  const _Float16* Bp = Wt + ((size_t)layer * RR + r) * HH * HH;
  int lane = t & 63, w = t >> 6;
  int wr = (w >> 2) * 128, wc = (w & 3) * 32;
  floatx4 acc[8][2] = {};

  int swz = ((lane & 3) ^ ((lane >> 3) & 3)) * 8;
  int ga0 = mtile * 256 + w * 32 + (lane >> 2);
  int ga1 = ga0 + 16;
  int gb = ntile * 128 + w * 16 + (lane >> 2);
  const _Float16* pa0 = x16 + (size_t)ga0 * HH + swz;
  const _Float16* pa1 = x16 + (size_t)ga1 * HH + swz;
  const _Float16* pb = Bp + (size_t)gb * HH + swz;
  auto issue = [&](int buf) {
    _Float16* lA = (_Float16*)(smraw + buf * 24576) + (w * 2) * 512;
    _Float16* lB = (_Float16*)(smraw + buf * 24576 + 16384) + w * 512;
    async16(pa0, lA); async16(pa1, lA + 512);
    async16(pb, lB);
    pa0 += 32; pa1 += 32; pb += 32;
  };

  issue(0); issue(1);
  asm volatile("s_waitcnt vmcnt(3)" ::: "memory");
  BAR_ONE();
  int cur = 0, nxt = 2;
  for (int s = 0; s < 24; ++s) {
    if (s + 2 < 24) { issue(nxt); nxt = nxt == 2 ? 0 : nxt + 1; }
    char* cb = smraw + cur * 24576;
    __builtin_amdgcn_s_setprio(1);
    mma16b((const _Float16*)cb, (const _Float16*)(cb + 16384), lane, wr, wc, acc);
    __builtin_amdgcn_s_setprio(0);
    if (s + 1 < 24) {
      if (s + 2 < 24) { asm volatile("s_waitcnt vmcnt(3)" ::: "memory"); }
      else            { asm volatile("s_waitcnt vmcnt(0)" ::: "memory"); }
      BAR_ONE();
    }
    cur = cur == 2 ? 0 : cur + 1;
  }
  __syncthreads();

  _Float16* outl = (_Float16*)smraw + (size_t)w * 4096;
#pragma unroll
  for (int i = 0; i < 8; ++i) {
#pragma unroll
    for (int j = 0; j < 2; ++j) {
      int rl = i * 16 + (lane >> 4) * 4;
      int cl = j * 16 + (lane & 15);
      int pos = rl ^ ((cl & 7) << 3);
      half4v v = {(_Float16)acc[i][j][0], (_Float16)acc[i][j][1],
                  (_Float16)acc[i][j][2], (_Float16)acc[i][j][3]};
      *(half4v*)&outl[cl * 128 + pos] = v;
    }
  }
  _Float16* outp = h1T + (size_t)(r - rbase) * HH * LDW2;
  int gmb = mtile * 256 + wr;
  int gnb = ntile * 128 + wc;
#pragma unroll
  for (int p = 0; p < 8; ++p) {
    int c = p * 4 + (lane >> 4);
    int mq = (lane & 15) * 8;
    int mpos = mq ^ ((c & 7) << 3);
    half8 v = *(const half8*)&outl[c * 128 + mpos];
    *(half8*)&outp[(size_t)(gnb + c) * LDW2 + gmb + mq] = v;
  }
}

// -------- GEMM D (R17 best): 256m x 128n, 8 waves x (64x64), ring-4 x 24KB,
//          counted vmcnt + mi-trim, UNIFORM staging --------
__global__ __launch_bounds__(512, 2) void gemm_att(const _Float16* __restrict__ att,
                                                   const _Float16* __restrict__ h1T,
                                                   float* __restrict__ partials, size_t psz,
                                                   int rs, int rcount, int rbase, int accflag,
                                                   int ngroups) {
  extern __shared__ __align__(16) char smraw[];  // 4 x (A 16K + B 8K) = 96 KB
  int t = threadIdx.x;
  int work = xcd_work(blockIdx.x, gridDim.x);
  int ntile = work % 6;
  int tmp = work / 6;
  int mtile = tmp & 1; tmp >>= 1;
  int g = tmp % ngroups;
  int b = tmp / ngroups;
  int rbeg = rs + (g * rcount) / ngroups;
  int rend = rs + ((g + 1) * rcount) / ngroups;
  int nr = rend - rbeg;
  int total = nr * 13;
  float* part = partials + (size_t)g * psz;
  int lane = t & 63, w = t >> 6;
  int wr = (w >> 1) * 64, wc = (w & 1) * 64;  // wave owns 64m x 64n of 256x128
  // valid-M fragment count for this wave (wave-uniform)
  int mrem = NN - (mtile * 256 + wr);
  int mi = mrem >= 64 ? 4 : (mrem <= 0 ? 0 : (mrem + 15) >> 4);
  floatx4 acc[4][4] = {}, sum[4][4] = {};

  int swz = ((lane & 3) ^ ((lane >> 3) & 3)) * 8;
  int ga0 = mtile * 256 + w * 32 + (lane >> 2);
  int ga1 = ga0 + 16;
  ga0 = ga0 > NN - 1 ? NN - 1 : ga0;  // clamp: garbage masked at compute/store
  ga1 = ga1 > NN - 1 ? NN - 1 : ga1;
  int gb = ntile * 128 + w * 16 + (lane >> 2);
  const _Float16* pa0 = att + ((size_t)b * RR + rbeg) * NN * APAD + (size_t)ga0 * APAD + swz;
  const _Float16* pa1 = att + ((size_t)b * RR + rbeg) * NN * APAD + (size_t)ga1 * APAD + swz;
  const _Float16* pb = h1T + (size_t)(rbeg - rbase) * HH * LDW2 + (size_t)gb * LDW2 + b * MB + swz;
  int nsk = 0;
  auto issue = [&](int buf) {
    _Float16* lA = (_Float16*)(smraw + buf * 24576) + (w * 2) * 512;
    _Float16* lB = (_Float16*)(smraw + buf * 24576 + 16384) + w * 512;
    async16(pa0, lA); async16(pa1, lA + 512);
    async16(pb, lB);
    if (++nsk == 13) {
      nsk = 0;
      pa0 += (size_t)NN * APAD - 384; pa1 += (size_t)NN * APAD - 384;
      pb += (size_t)HH * LDW2 - 384;
    } else { pa0 += 32; pa1 += 32; pb += 32; }
  };

  issue(0); issue(1); issue(2);
  vm_wait3(2);
  BAR_ONE();
  int cks = 0;
  for (int s = 0; s < total; ++s) {
    if (s + 3 < total) issue((s + 3) & 3);
    char* cb = smraw + (s & 3) * 24576;
    __builtin_amdgcn_s_setprio(1);
    mma_tiles_mi((const _Float16*)cb, (const _Float16*)(cb + 16384), lane, wr, wc, mi, acc);
    __builtin_amdgcn_s_setprio(0);
    if (cks == 12) {
#pragma unroll
      for (int i = 0; i < 4; ++i) {
        if (i < mi) {
#pragma unroll
          for (int j = 0; j < 4; ++j) {
#pragma unroll
            for (int q2 = 0; q2 < 4; ++q2) sum[i][j][q2] += fmaxf(acc[i][j][q2], 0.0f);
            acc[i][j] = (floatx4){0.f, 0.f, 0.f, 0.f};
          }
        }
      }
      cks = 0;
    } else ++cks;
    if (s + 1 < total) {
      int ahead = total - s - 2;
      vm_wait3(ahead > 2 ? 2 : ahead);
      BAR_ONE();  // publishes buf s+1; step-s ds_reads retired before last MFMA issued
    }
  }
#pragma unroll
  for (int i = 0; i < 4; ++i) {
    if (i >= mi) continue;
    int rl = wr + i * 16 + (lane >> 4) * 4;
    int grow = mtile * 256 + rl;
#pragma unroll
    for (int j = 0; j < 4; ++j) {
      int gcol = ntile * 128 + wc + j * 16 + (lane & 15);
#pragma unroll
      for (int q2 = 0; q2 < 4; ++q2) {
        if (grow + q2 < NN) {
          size_t idx = ((size_t)b * NN + grow + q2) * HH + gcol;
          float v = sum[i][j][q2];
          if (accflag) v += part[idx];
          part[idx] = v;
        }
      }
    }
  }
}

// -------- LayerNorm over H of z = relu(sum_g partial[g]) / R --------
__global__ __launch_bounds__(256) void lnorm(const float* __restrict__ partials, size_t psz, int np,
                                             _Float16* __restrict__ x16, float* __restrict__ out) {
  int row = blockIdx.x;
  int t = threadIdx.x;
  int b = row / NN;
  int xrow = row + b * 16;
  float v[3];
  float s = 0.f, s2 = 0.f;
#pragma unroll
  for (int j = 0; j < 3; ++j) {
    float a = 0.f;
    for (int gidx = 0; gidx < np; ++gidx) a += partials[(size_t)gidx * psz + (size_t)row * HH + t + j * 256];
    v[j] = fmaxf(a, 0.f) * (1.0f / RR);
    s += v[j];
    s2 += v[j] * v[j];
  }
#pragma unroll
  for (int o = 32; o; o >>= 1) {
    s += __shfl_xor(s, o);
    s2 += __shfl_xor(s2, o);
  }
  __shared__ float rs_[4], rs2_[4];
  int lane = t & 63, wid = t >> 6;
  if (!lane) { rs_[wid] = s; rs2_[wid] = s2; }
  __syncthreads();
  s = rs_[0] + rs_[1] + rs_[2] + rs_[3];
  s2 = rs2_[0] + rs2_[1] + rs2_[2] + rs2_[3];
  float mu = s * (1.0f / HH);
  float var = s2 * (1.0f / HH) - mu * mu;
  float rstd = rsqrtf(var + 1e-5f);
#pragma unroll
  for (int j = 0; j < 3; ++j) {
    float o = (v[j] - mu) * rstd;
    out[(size_t)row * HH + t + j * 256] = o;
    x16[(size_t)xrow * HH + t + j * 256] = (_Float16)o;
  }
}

extern "C" void kernel_launch(void* const* d_in, const int* in_sizes, int n_in,
                              void* d_out, int out_size, void* d_ws, size_t ws_size,
                              hipStream_t stream) {
  const float* adj = (const float*)d_in[0];
  const float* feature = (const float*)d_in[1];
  const float* dmask = (const float*)d_in[2];
  const float* W = (const float*)d_in[3];
  float* out = (float*)d_out;

  (void)hipFuncSetAttribute((const void*)gemm_xw,
                            hipFuncAttributeMaxDynamicSharedMemorySize, 73728);
  (void)hipFuncSetAttribute((const void*)gemm_att,
                            hipFuncAttributeMaxDynamicSharedMemorySize, 98304);

  uintptr_t base = (uintptr_t)d_ws;
  uintptr_t p = base;
  auto alloc = [&](size_t bytes) -> void* {
    uintptr_t q = (p + 255) & ~(uintptr_t)255;
    p = q + bytes;
    return (void*)q;
  };
  _Float16* att = (_Float16*)alloc((size_t)BS * RR * NN * APAD * 2);  // 131.9 MB
  _Float16* Wt = (_Float16*)alloc((size_t)2 * RR * HH * HH * 2);      // 108.5 MB
  _Float16* x16 = (_Float16*)alloc((size_t)MFLAT2 * HH * 2);          // 5.1 MB
  size_t psz = (size_t)(BS * NN) * HH;
  size_t pszB = psz * 4;
  size_t used = p - base;
  size_t rem = ws_size > used ? ws_size - used : 0;
  size_t perR = (size_t)HH * LDW2 * 2;  // 5.11 MB / r
  size_t h1full = (size_t)RR * perR;    // 235 MB

  conv_w<<<dim3(576, 2 * RR), 256, 0, stream>>>(W, Wt);
  conv_x<<<MFLAT2 * HH / 4 / 256, 256, 0, stream>>>(feature, x16);
  att_softmax<<<dim3(NN, BS), 512, 0, stream>>>(adj, dmask, att);

  if (rem >= h1full + 4 * pszB + 512) {
    _Float16* h1T = (_Float16*)alloc(h1full);
    int ngroups = (int)(((ws_size - (p - base)) - 256) / pszB);
    if (ngroups > 8) ngroups = 8;
    float* partials = (float*)alloc((size_t)ngroups * pszB);
    for (int layer = 0; layer < 2; ++layer) {
      gemm_xw<<<78 * RR, 512, 73728, stream>>>(x16, Wt, h1T, layer, 0, 0);
      gemm_att<<<96 * ngroups, 512, 98304, stream>>>(att, h1T, partials, psz, 0, RR, 0, 0, ngroups);
      lnorm<<<BS * NN, 256, 0, stream>>>(partials, psz, ngroups, x16, out);
    }
  } else {
    float* partials = (float*)alloc(pszB);
    size_t rem2 = ws_size > (p - base) ? ws_size - (p - base) : 0;
    int RCmax = (int)(rem2 / perR);
    if (RCmax > RR) RCmax = RR;
    if (RCmax < 1) RCmax = 1;
    _Float16* h1T = (_Float16*)alloc((size_t)RCmax * perR);
    for (int layer = 0; layer < 2; ++layer) {
      for (int r0 = 0; r0 < RR; r0 += RCmax) {
        int rc = RR - r0 < RCmax ? RR - r0 : RCmax;
        gemm_xw<<<78 * rc, 512, 73728, stream>>>(x16, Wt, h1T, layer, r0, r0);
        gemm_att<<<96 * 1, 512, 98304, stream>>>(att, h1T, partials, psz, r0, rc, r0, r0 > 0, 1);
      }
      lnorm<<<BS * NN, 256, 0, stream>>>(partials, psz, 1, x16, out);
    }
  }
}